// Round 4
// baseline (2191.459 us; speedup 1.0000x reference)
//
#include <hip/hip_runtime.h>
#include <math.h>

#define DD   512
#define NTOT 65536
#define RR   64
#define NB   2
#define EPSV 1e-6f

typedef unsigned short u16;
typedef __attribute__((ext_vector_type(8))) short bf16x8;
typedef __attribute__((ext_vector_type(8))) unsigned short us8;
typedef __attribute__((ext_vector_type(4))) unsigned short us4;
typedef __attribute__((ext_vector_type(4))) float f32x4;

__device__ inline u16 f2bf(float f) {
    union { float f; unsigned u; } x; x.f = f;
    unsigned r = x.u + 0x7FFFu + ((x.u >> 16) & 1u);   // RNE (no NaN here)
    return (u16)(r >> 16);
}
__device__ inline float bf2f(u16 h) {
    union { unsigned u; float f; } x; x.u = ((unsigned)h) << 16;
    return x.f;
}
// clamp raw bf16 to >= bf16(1e-6)=0x3586; signed compare handles negatives.
__device__ inline bf16x8 clampbf8(bf16x8 v) {
#pragma unroll
    for (int i = 0; i < 8; ++i) {
        short t = v[i];
        v[i] = (t < (short)0x3586) ? (short)0x3586 : t;
    }
    return v;
}

#define MFMA16(a, b, c) __builtin_amdgcn_mfma_f32_16x16x32_bf16((a), (b), (c), 0, 0, 0)

// ---------------------------------------------------------------------------
// convert_x: x fp32 [s][d][n] -> xd bf16 CLAMPED [s][d][n] + xT bf16 RAW
// [s][n][d]. Both live in d_out. grid (NTOT/64, DD/64, NB).
// ---------------------------------------------------------------------------
__global__ __launch_bounds__(256) void convert_x_kernel(const float* __restrict__ x,
                                                        u16* __restrict__ xd,
                                                        u16* __restrict__ xT) {
    int s = blockIdx.z, d0 = blockIdx.y * 64, n0 = blockIdx.x * 64;
    const float* xp = x + ((size_t)s * DD + d0) * NTOT + n0;
    u16* xdp = xd + ((size_t)s * DD + d0) * NTOT + n0;
    u16* xtp = xT + ((size_t)s * NTOT + n0) * DD + d0;
    __shared__ u16 L[64][66];
    int tid = threadIdx.x;
#pragma unroll
    for (int k = 0; k < 4; ++k) {
        int f4 = tid + k * 256;
        int dr = f4 >> 4, c4 = (f4 & 15) * 4;
        float4 v = *(const float4*)&xp[(size_t)dr * NTOT + c4];
        u16 h0 = f2bf(v.x), h1 = f2bf(v.y), h2 = f2bf(v.z), h3 = f2bf(v.w);
        // clamped copy for xd
        xdp[(size_t)dr * NTOT + c4 + 0] = f2bf(fmaxf(v.x, EPSV));
        xdp[(size_t)dr * NTOT + c4 + 1] = f2bf(fmaxf(v.y, EPSV));
        xdp[(size_t)dr * NTOT + c4 + 2] = f2bf(fmaxf(v.z, EPSV));
        xdp[(size_t)dr * NTOT + c4 + 3] = f2bf(fmaxf(v.w, EPSV));
        L[dr][c4 + 0] = h0; L[dr][c4 + 1] = h1;
        L[dr][c4 + 2] = h2; L[dr][c4 + 3] = h3;
    }
    __syncthreads();
#pragma unroll
    for (int k = 0; k < 2; ++k) {
        int f8 = tid + k * 256;
        int nr = f8 >> 3, d8 = (f8 & 7) * 8;
        us8 w;
#pragma unroll
        for (int i = 0; i < 8; ++i) w[i] = L[d8 + i][nr];
        *(us8*)&xtp[(size_t)nr * DD + d8] = w;
    }
}

// ---------------------------------------------------------------------------
// colnorm: dst[:,r] = src[:,r] / max(||src[:,r]||, 1e-12) per (batch, r).
// ---------------------------------------------------------------------------
__global__ __launch_bounds__(64) void colnorm_kernel(const float* __restrict__ src,
                                                     float* __restrict__ dst) {
    int col = blockIdx.x;
    int s = col >> 6, r = col & 63;
    const float* p = src + (size_t)s * DD * RR + r;
    float* q = dst + (size_t)s * DD * RR + r;
    int lane = threadIdx.x;
    float v[8];
    float ss = 0.f;
#pragma unroll
    for (int k = 0; k < 8; ++k) {
        v[k] = p[(size_t)(lane + 64 * k) * RR];
        ss += v[k] * v[k];
    }
#pragma unroll
    for (int m = 1; m < 64; m <<= 1) ss += __shfl_xor(ss, m);
    float inv = 1.f / fmaxf(sqrtf(ss), 1e-12f);
#pragma unroll
    for (int k = 0; k < 8; ++k)
        q[(size_t)(lane + 64 * k) * RR] = v[k] * inv;
}

// ---------------------------------------------------------------------------
// bcast0: b fp32 [d][r] -> b_bf [d][r], bT_bf [r][d]. grid (NB), 256 thr.
// ---------------------------------------------------------------------------
__global__ __launch_bounds__(256) void bcast0_kernel(const float* __restrict__ b,
                                                     u16* __restrict__ b_bf,
                                                     u16* __restrict__ bT_bf) {
    int s = blockIdx.x, tid = threadIdx.x;
    const float* bp = b + (size_t)s * DD * RR;
    u16* bb = b_bf + (size_t)s * DD * RR;
    u16* bt = bT_bf + (size_t)s * RR * DD;
    for (int i = tid; i < DD * RR; i += 256) {
        int d = i >> 6, r = i & 63;
        u16 h = f2bf(bp[i]);
        bb[i] = h;
        bt[r * DD + d] = h;
    }
}

// ---------------------------------------------------------------------------
// gram: btb_bf[k][j] = bf16( sum_d bT[k][d]*bT[j][d] )  via MFMA, K=512.
// Symmetric by construction. grid (NB), 256 thr (4 waves x 16 k-rows).
// ---------------------------------------------------------------------------
__global__ __launch_bounds__(256) void gram_kernel(const u16* __restrict__ bT_bf,
                                                   u16* __restrict__ btb_bf) {
    int s = blockIdx.x;
    int tid = threadIdx.x;
    int w = tid >> 6, lane = tid & 63, g = lane >> 4, l15 = lane & 15;
    const u16* bt = bT_bf + (size_t)s * RR * DD;
    f32x4 zero = {0.f, 0.f, 0.f, 0.f};
    f32x4 acc[4];
#pragma unroll
    for (int cs = 0; cs < 4; ++cs) acc[cs] = zero;
    for (int k0 = 0; k0 < DD; k0 += 32) {
        bf16x8 a = *(const bf16x8*)&bt[(w * 16 + l15) * DD + k0 + g * 8];
        bf16x8 b[4];
#pragma unroll
        for (int cs = 0; cs < 4; ++cs)
            b[cs] = *(const bf16x8*)&bt[(cs * 16 + l15) * DD + k0 + g * 8];
#pragma unroll
        for (int cs = 0; cs < 4; ++cs) acc[cs] = MFMA16(a, b[cs], acc[cs]);
    }
    u16* op = btb_bf + (size_t)s * RR * RR;
#pragma unroll
    for (int cs = 0; cs < 4; ++cs)
#pragma unroll
        for (int e = 0; e < 4; ++e)
            op[(w * 16 + g * 4 + e) * RR + cs * 16 + l15] = f2bf(acc[cs][e]);
}

// ---------------------------------------------------------------------------
// init_mfma: coef = softmax_r(x^T b) on RAW bf16 xT via MFMA; writes cTf [r][n]
// and cnb [n][r] (both unclamped). Wave: 64r x 32n. grid (NTOT/128, NB).
// ---------------------------------------------------------------------------
__global__ __launch_bounds__(256) void init_mfma_kernel(const u16* __restrict__ xT,
                                                        const u16* __restrict__ bT,
                                                        u16* __restrict__ cT,
                                                        u16* __restrict__ cnb) {
    int s = blockIdx.y;
    int n0 = blockIdx.x * 128;
    int tid = threadIdx.x;
    int w = tid >> 6, lane = tid & 63, g = lane >> 4, l15 = lane & 15;
    int nw = n0 + w * 32;
    const u16* xTp = xT + (size_t)s * NTOT * DD;
    const u16* bTp = bT + (size_t)s * RR * DD;
    u16* cTp = cT + (size_t)s * RR * NTOT;
    u16* cnp = cnb + (size_t)s * NTOT * RR;

    f32x4 zero = {0.f, 0.f, 0.f, 0.f};
    f32x4 acc[4][2];
#pragma unroll
    for (int rs = 0; rs < 4; ++rs)
#pragma unroll
        for (int ns = 0; ns < 2; ++ns) acc[rs][ns] = zero;

    for (int k0 = 0; k0 < DD; k0 += 32) {
        bf16x8 a[4], b[2];
#pragma unroll
        for (int rs = 0; rs < 4; ++rs)
            a[rs] = *(const bf16x8*)&bTp[(rs * 16 + l15) * DD + k0 + g * 8];
#pragma unroll
        for (int ns = 0; ns < 2; ++ns)
            b[ns] = *(const bf16x8*)&xTp[(size_t)(nw + ns * 16 + l15) * DD + k0 + g * 8];
#pragma unroll
        for (int rs = 0; rs < 4; ++rs)
#pragma unroll
            for (int ns = 0; ns < 2; ++ns)
                acc[rs][ns] = MFMA16(a[rs], b[ns], acc[rs][ns]);
    }

#pragma unroll
    for (int ns = 0; ns < 2; ++ns) {
        int n = nw + ns * 16 + l15;
        float m = acc[0][ns][0];
#pragma unroll
        for (int rs = 0; rs < 4; ++rs)
#pragma unroll
            for (int e = 0; e < 4; ++e) m = fmaxf(m, acc[rs][ns][e]);
        m = fmaxf(m, __shfl_xor(m, 16));
        m = fmaxf(m, __shfl_xor(m, 32));
        float ev[4][4];
        float ssum = 0.f;
#pragma unroll
        for (int rs = 0; rs < 4; ++rs)
#pragma unroll
            for (int e = 0; e < 4; ++e) {
                ev[rs][e] = __expf(acc[rs][ns][e] - m);
                ssum += ev[rs][e];
            }
        ssum += __shfl_xor(ssum, 16);
        ssum += __shfl_xor(ssum, 32);
        float inv = 1.f / ssum;
#pragma unroll
        for (int rs = 0; rs < 4; ++rs) {
            us4 pack;
#pragma unroll
            for (int e = 0; e < 4; ++e) {
                u16 h = f2bf(ev[rs][e] * inv);
                cTp[(size_t)(rs * 16 + g * 4 + e) * NTOT + n] = h;
                pack[e] = h;
            }
            *(us4*)&cnp[(size_t)n * RR + rs * 16 + g * 4] = pack;
        }
    }
}

// ---------------------------------------------------------------------------
// xtb_mfma: fused denC + numC + c-update.
//  phase1: denT[r][n] = BtB_bf @ cnb            (K=64)
//  phase2: T^T[r][n]  = bT_bf @ clamp(xT_raw)   (K=512)
//  epilogue: v = clamp?(cT)*T/(den+EPS); cT=v (if WRITE_CT);
//            cnb = clamp(v) if CLAMP_OUT else v.
// grid (NTOT/128, NB), 256 thr.
// ---------------------------------------------------------------------------
template <int CLAMPC, int CLAMP_OUT, int WRITE_CT>
__global__ __launch_bounds__(256) void xtb_mfma_kernel(const u16* __restrict__ xT,
                                                       const u16* __restrict__ bT,
                                                       const u16* __restrict__ btbbf,
                                                       u16* __restrict__ cnb,
                                                       u16* __restrict__ cT) {
    int s = blockIdx.y;
    int n0 = blockIdx.x * 128;
    int tid = threadIdx.x;
    int w = tid >> 6, lane = tid & 63, g = lane >> 4, l15 = lane & 15;
    int nw = n0 + w * 32;
    const u16* xTp = xT + (size_t)s * NTOT * DD;
    const u16* bTp = bT + (size_t)s * RR * DD;
    const u16* bb = btbbf + (size_t)s * RR * RR;
    u16* cnp = cnb + (size_t)s * NTOT * RR;
    u16* cTp = cT + (size_t)s * RR * NTOT;

    f32x4 zero = {0.f, 0.f, 0.f, 0.f};
    f32x4 accD[4][2], accT[4][2];
#pragma unroll
    for (int rs = 0; rs < 4; ++rs)
#pragma unroll
        for (int ns = 0; ns < 2; ++ns) { accD[rs][ns] = zero; accT[rs][ns] = zero; }

    // phase 1: den (K=64 over r'; cnb holds prev c, already clamp-staged)
#pragma unroll
    for (int k0 = 0; k0 < 64; k0 += 32) {
        bf16x8 a[4], b[2];
#pragma unroll
        for (int rs = 0; rs < 4; ++rs)
            a[rs] = *(const bf16x8*)&bb[(rs * 16 + l15) * RR + k0 + g * 8];
#pragma unroll
        for (int ns = 0; ns < 2; ++ns)
            b[ns] = *(const bf16x8*)&cnp[(size_t)(nw + ns * 16 + l15) * RR + k0 + g * 8];
#pragma unroll
        for (int rs = 0; rs < 4; ++rs)
#pragma unroll
            for (int ns = 0; ns < 2; ++ns)
                accD[rs][ns] = MFMA16(a[rs], b[ns], accD[rs][ns]);
    }
    // phase 2: T = b^T xc  (clamp raw x on the fly)
    for (int k0 = 0; k0 < DD; k0 += 32) {
        bf16x8 a[4], b[2];
#pragma unroll
        for (int rs = 0; rs < 4; ++rs)
            a[rs] = *(const bf16x8*)&bTp[(rs * 16 + l15) * DD + k0 + g * 8];
#pragma unroll
        for (int ns = 0; ns < 2; ++ns)
            b[ns] = clampbf8(*(const bf16x8*)&xTp[(size_t)(nw + ns * 16 + l15) * DD + k0 + g * 8]);
#pragma unroll
        for (int rs = 0; rs < 4; ++rs)
#pragma unroll
            for (int ns = 0; ns < 2; ++ns)
                accT[rs][ns] = MFMA16(a[rs], b[ns], accT[rs][ns]);
    }
    // epilogue
#pragma unroll
    for (int ns = 0; ns < 2; ++ns) {
        int n = nw + ns * 16 + l15;
#pragma unroll
        for (int rs = 0; rs < 4; ++rs) {
            us4 pack;
#pragma unroll
            for (int e = 0; e < 4; ++e) {
                int r = rs * 16 + g * 4 + e;
                size_t off = (size_t)r * NTOT + n;
                float cin = bf2f(cTp[off]);
                if (CLAMPC) cin = fmaxf(cin, EPSV);
                float v = cin * accT[rs][ns][e] / (accD[rs][ns][e] + EPSV);
                u16 h = f2bf(v);
                if (WRITE_CT) cTp[off] = h;
                if (CLAMP_OUT) h = (h < (u16)0x3586u) ? (u16)0x3586u : h;  // v>0
                pack[e] = h;
            }
            *(us4*)&cnp[(size_t)n * RR + rs * 16 + g * 4] = pack;
        }
    }
}

// ---------------------------------------------------------------------------
// ctc_mfma: CtC[i][j] += sum_n c[n][i]*c[n][j] from cTf. K-split atomics.
// grid (64, NB), chunk 1024, 256 thr.
// ---------------------------------------------------------------------------
__global__ __launch_bounds__(256) void ctc_mfma_kernel(const u16* __restrict__ cT,
                                                       float* __restrict__ ctc) {
    int s = blockIdx.y;
    int kbase = blockIdx.x * 1024;
    int tid = threadIdx.x;
    int w = tid >> 6, lane = tid & 63, g = lane >> 4, l15 = lane & 15;
    const u16* cTp = cT + (size_t)s * RR * NTOT;
    f32x4 zero = {0.f, 0.f, 0.f, 0.f};
    f32x4 acc[4];
#pragma unroll
    for (int cs = 0; cs < 4; ++cs) acc[cs] = zero;
    for (int k0 = kbase; k0 < kbase + 1024; k0 += 32) {
        bf16x8 a = *(const bf16x8*)&cTp[(size_t)(w * 16 + l15) * NTOT + k0 + g * 8];
        bf16x8 b[4];
#pragma unroll
        for (int cs = 0; cs < 4; ++cs)
            b[cs] = *(const bf16x8*)&cTp[(size_t)(cs * 16 + l15) * NTOT + k0 + g * 8];
#pragma unroll
        for (int cs = 0; cs < 4; ++cs) acc[cs] = MFMA16(a, b[cs], acc[cs]);
    }
    float* op = ctc + (size_t)s * RR * RR;
#pragma unroll
    for (int cs = 0; cs < 4; ++cs)
#pragma unroll
        for (int e = 0; e < 4; ++e)
            atomicAdd(&op[(w * 16 + g * 4 + e) * RR + cs * 16 + l15], acc[cs][e]);
}

// ---------------------------------------------------------------------------
// xtc_mfma: numB[d][r] += sum_n xd[d][n]*c[n][r]. 512 thr (8 waves, 128 d),
// grid (16 ksplit, 4 dtile, NB) = 128 blocks, chunk 4096.
// ---------------------------------------------------------------------------
__global__ __launch_bounds__(512) void xtc_mfma_kernel(const u16* __restrict__ xd,
                                                       const u16* __restrict__ cT,
                                                       float* __restrict__ numB) {
    int s = blockIdx.z;
    int dtile = blockIdx.y * 128;
    int kbase = blockIdx.x * 4096;
    int tid = threadIdx.x;
    int w = tid >> 6, lane = tid & 63, g = lane >> 4, l15 = lane & 15;
    const u16* xdp = xd + (size_t)s * DD * NTOT;
    const u16* cTp = cT + (size_t)s * RR * NTOT;
    int drow = dtile + w * 16 + l15;
    f32x4 zero = {0.f, 0.f, 0.f, 0.f};
    f32x4 acc[4];
#pragma unroll
    for (int rs = 0; rs < 4; ++rs) acc[rs] = zero;
    for (int k0 = kbase; k0 < kbase + 4096; k0 += 32) {
        bf16x8 a = *(const bf16x8*)&xdp[(size_t)drow * NTOT + k0 + g * 8];
        bf16x8 b[4];
#pragma unroll
        for (int rs = 0; rs < 4; ++rs)
            b[rs] = *(const bf16x8*)&cTp[(size_t)(rs * 16 + l15) * NTOT + k0 + g * 8];
#pragma unroll
        for (int rs = 0; rs < 4; ++rs) acc[rs] = MFMA16(a, b[rs], acc[rs]);
    }
    float* op = numB + (size_t)s * DD * RR;
#pragma unroll
    for (int rs = 0; rs < 4; ++rs)
#pragma unroll
        for (int e = 0; e < 4; ++e)
            atomicAdd(&op[(dtile + w * 16 + g * 4 + e) * RR + rs * 16 + l15], acc[rs][e]);
}

// ---------------------------------------------------------------------------
// bupd_a: bnew = max(b*numB/(b@CtC+EPS), EPS) in-place on b0 (fp32), plus
// per-block column-norm^2 partials. grid (8, NB), 256 thr.
// ---------------------------------------------------------------------------
__global__ __launch_bounds__(256) void bupd_a_kernel(float* __restrict__ b0,
                                                     const float* __restrict__ numB,
                                                     const float* __restrict__ ctcG,
                                                     float* __restrict__ norm2p) {
    int s = blockIdx.y;
    int d0 = blockIdx.x * 64;
    float* bp = b0 + ((size_t)s * DD + d0) * RR;
    const float* np_ = numB + ((size_t)s * DD + d0) * RR;
    const float* cc = ctcG + (size_t)s * RR * RR;
    __shared__ __align__(16) float Bsh[64][68];
    __shared__ __align__(16) float Ct[64][68];
    __shared__ float red[16][64];
    int tid = threadIdx.x, tx = tid & 15, ty = tid >> 4;
#pragma unroll
    for (int k = 0; k < 16; ++k) {
        int idx = tid + k * 256;
        int r_ = idx >> 6, col = idx & 63;
        Bsh[r_][col] = bp[idx];
        Ct[r_][col] = cc[idx];
    }
    __syncthreads();
    float part[4] = {};
#pragma unroll
    for (int i = 0; i < 4; ++i) {
        int d = 4 * ty + i;
        float den[4] = {};
#pragma unroll
        for (int k = 0; k < 64; ++k) {
            float bv = Bsh[d][k];
            float4 ct = *(const float4*)&Ct[k][4 * tx];
            den[0] += bv * ct.x;
            den[1] += bv * ct.y;
            den[2] += bv * ct.z;
            den[3] += bv * ct.w;
        }
        float4 b4 = *(const float4*)&Bsh[d][4 * tx];
        float4 n4 = *(const float4*)&np_[(size_t)d * RR + 4 * tx];
        float4 o;
        o.x = fmaxf(b4.x * n4.x / (den[0] + EPSV), EPSV);
        o.y = fmaxf(b4.y * n4.y / (den[1] + EPSV), EPSV);
        o.z = fmaxf(b4.z * n4.z / (den[2] + EPSV), EPSV);
        o.w = fmaxf(b4.w * n4.w / (den[3] + EPSV), EPSV);
        *(float4*)&bp[(size_t)d * RR + 4 * tx] = o;
        part[0] += o.x * o.x; part[1] += o.y * o.y;
        part[2] += o.z * o.z; part[3] += o.w * o.w;
    }
#pragma unroll
    for (int j = 0; j < 4; ++j) red[ty][4 * tx + j] = part[j];
    __syncthreads();
    if (tid < 64) {
        float ssum = 0.f;
#pragma unroll
        for (int k = 0; k < 16; ++k) ssum += red[k][tid];
        norm2p[((size_t)s * 8 + blockIdx.x) * 64 + tid] = ssum;
    }
}

// ---------------------------------------------------------------------------
// bupd_c: inv = 1/max(sqrt(sum norm2p),1e-12); b0 *= inv; write b_bf, bT_bf.
// grid (8, NB), 256 thr.
// ---------------------------------------------------------------------------
__global__ __launch_bounds__(256) void bupd_c_kernel(float* __restrict__ b0,
                                                     const float* __restrict__ norm2p,
                                                     u16* __restrict__ b_bf,
                                                     u16* __restrict__ bT_bf) {
    int s = blockIdx.y;
    int d0 = blockIdx.x * 64;
    float* bp = b0 + ((size_t)s * DD + d0) * RR;
    u16* bb = b_bf + ((size_t)s * DD + d0) * RR;
    u16* bt = bT_bf + (size_t)s * RR * DD;
    __shared__ float invl[64];
    int tid = threadIdx.x, tx = tid & 15, ty = tid >> 4;
    if (tid < 64) {
        float t = 0.f;
#pragma unroll
        for (int k = 0; k < 8; ++k) t += norm2p[((size_t)s * 8 + k) * 64 + tid];
        invl[tid] = 1.f / fmaxf(sqrtf(t), 1e-12f);
    }
    __syncthreads();
#pragma unroll
    for (int i = 0; i < 4; ++i) {
        int d = 4 * ty + i;
        float4 v = *(const float4*)&bp[(size_t)d * RR + 4 * tx];
        v.x *= invl[4 * tx + 0];
        v.y *= invl[4 * tx + 1];
        v.z *= invl[4 * tx + 2];
        v.w *= invl[4 * tx + 3];
        *(float4*)&bp[(size_t)d * RR + 4 * tx] = v;
        us4 pack;
        pack[0] = f2bf(v.x); pack[1] = f2bf(v.y);
        pack[2] = f2bf(v.z); pack[3] = f2bf(v.w);
        *(us4*)&bb[(size_t)d * RR + 4 * tx] = pack;
        bt[(4 * tx + 0) * DD + d0 + d] = pack[0];
        bt[(4 * tx + 1) * DD + d0 + d] = pack[1];
        bt[(4 * tx + 2) * DD + d0 + d] = pack[2];
        bt[(4 * tx + 3) * DD + d0 + d] = pack[3];
    }
}

// ---------------------------------------------------------------------------
// xhat_mfma: out[d][n] = sum_r b[d][r]*c_new[n][r]. K=64.
// grid (NTOT/64, DD/64, NB).
// ---------------------------------------------------------------------------
__global__ __launch_bounds__(256) void xhat_mfma_kernel(const u16* __restrict__ b_bf,
                                                        const u16* __restrict__ cnb,
                                                        float* __restrict__ outp) {
    int s = blockIdx.z;
    int d0 = blockIdx.y * 64;
    int n0 = blockIdx.x * 64;
    int tid = threadIdx.x;
    int w = tid >> 6, lane = tid & 63, g = lane >> 4, l15 = lane & 15;
    const u16* bp = b_bf + (size_t)s * DD * RR;
    const u16* cp = cnb + (size_t)s * NTOT * RR;
    f32x4 zero = {0.f, 0.f, 0.f, 0.f};
    f32x4 acc[4];
#pragma unroll
    for (int ns = 0; ns < 4; ++ns) acc[ns] = zero;
#pragma unroll
    for (int k0 = 0; k0 < 64; k0 += 32) {
        bf16x8 a = *(const bf16x8*)&bp[(d0 + w * 16 + l15) * RR + k0 + g * 8];
        bf16x8 b[4];
#pragma unroll
        for (int ns = 0; ns < 4; ++ns)
            b[ns] = *(const bf16x8*)&cp[(size_t)(n0 + ns * 16 + l15) * RR + k0 + g * 8];
#pragma unroll
        for (int ns = 0; ns < 4; ++ns) acc[ns] = MFMA16(a, b[ns], acc[ns]);
    }
    float* op = outp + (size_t)s * DD * NTOT;
#pragma unroll
    for (int ns = 0; ns < 4; ++ns)
#pragma unroll
        for (int e = 0; e < 4; ++e)
            op[(size_t)(d0 + w * 16 + g * 4 + e) * NTOT + n0 + ns * 16 + l15] = acc[ns][e];
}

// ---------------------------------------------------------------------------
extern "C" void kernel_launch(void* const* d_in, const int* in_sizes, int n_in,
                              void* d_out, int out_size, void* d_ws, size_t ws_size,
                              hipStream_t stream) {
    const float* x = (const float*)d_in[0];      // (2,512,65536) fp32
    const float* bases = (const float*)d_in[1];  // (2,512,64)
    float* out = (float*)d_out;
    char* ws = (char*)d_ws;

    // out doubles as bf16 x storage until xhat overwrites it
    u16* xT = (u16*)d_out;                             // [NB][NTOT][DD] RAW
    u16* xd = (u16*)d_out + (size_t)NB * NTOT * DD;    // [NB][DD][NTOT] clamped

    // ws layout (<= 34,406,400 B proven-safe footprint)
    u16* cTf = (u16*)ws;                          // 16,777,216
    u16* cnb = (u16*)(ws + 16777216);             // 16,777,216
    float* b0 = (float*)(ws + 33554432);          //    262,144
    float* ctc = (float*)(ws + 33816576);         //     32,768
    float* nB = (float*)(ws + 33849344);          //    262,144 (contig w/ ctc)
    u16* bT_bf = (u16*)(ws + 34111488);           //    131,072
    u16* b_bf = (u16*)(ws + 34242560);            //    131,072
    u16* btb_bf = (u16*)(ws + 34373632);          //     16,384
    float* norm2p = (float*)(ws + 34390016);      //      4,096  -> 34,394,112

    // 1) bf16 copies of x into out (xT raw, xd clamped)
    convert_x_kernel<<<dim3(NTOT / 64, DD / 64, NB), 256, 0, stream>>>(x, xd, xT);

    // 2) b = l2norm(bases); casts; BtB via MFMA gram
    colnorm_kernel<<<NB * RR, 64, 0, stream>>>(bases, b0);
    bcast0_kernel<<<NB, 256, 0, stream>>>(b0, b_bf, bT_bf);
    gram_kernel<<<NB, 256, 0, stream>>>(bT_bf, btb_bf);

    // 3) coef = softmax(x^T b) via MFMA on raw xT
    init_mfma_kernel<<<dim3(NTOT / 128, NB), 256, 0, stream>>>(xT, bT_bf, cTf, cnb);

    // 4) 6 MU steps
    for (int step = 0; step < 6; ++step) {
        if (step > 0)
            xtb_mfma_kernel<1, 1, 1><<<dim3(NTOT / 128, NB), 256, 0, stream>>>(
                xT, bT_bf, btb_bf, cnb, cTf);
        else
            xtb_mfma_kernel<0, 1, 1><<<dim3(NTOT / 128, NB), 256, 0, stream>>>(
                xT, bT_bf, btb_bf, cnb, cTf);
        hipMemsetAsync(ctc, 0, 32768 + 262144, stream);   // ctc + numB contiguous
        ctc_mfma_kernel<<<dim3(64, NB), 256, 0, stream>>>(cTf, ctc);
        xtc_mfma_kernel<<<dim3(16, 4, NB), 512, 0, stream>>>(xd, cTf, nB);
        bupd_a_kernel<<<dim3(8, NB), 256, 0, stream>>>(b0, nB, ctc, norm2p);
        bupd_c_kernel<<<dim3(8, NB), 256, 0, stream>>>(b0, norm2p, b_bf, bT_bf);
        gram_kernel<<<NB, 256, 0, stream>>>(bT_bf, btb_bf);
    }

    // 5) compute_coef: cnb <- c_new (unclamped) for xhat
    xtb_mfma_kernel<1, 0, 0><<<dim3(NTOT / 128, NB), 256, 0, stream>>>(
        xT, bT_bf, btb_bf, cnb, cTf);

    // 6) x_hat = b @ c_new^T
    xhat_mfma_kernel<<<dim3(NTOT / 64, DD / 64, NB), 256, 0, stream>>>(b_bf, cnb, out);
}

// Round 5
// 1547.461 us; speedup vs baseline: 1.4162x; 1.4162x over previous
//
#include <hip/hip_runtime.h>
#include <math.h>

#define DD   512
#define NTOT 65536
#define RR   64
#define NB   2
#define EPSV 1e-6f

typedef unsigned short u16;
typedef __attribute__((ext_vector_type(8))) short bf16x8;
typedef __attribute__((ext_vector_type(8))) unsigned short us8;
typedef __attribute__((ext_vector_type(4))) unsigned short us4;
typedef __attribute__((ext_vector_type(4))) float f32x4;

__device__ inline u16 f2bf(float f) {
    union { float f; unsigned u; } x; x.f = f;
    unsigned r = x.u + 0x7FFFu + ((x.u >> 16) & 1u);   // RNE (no NaN here)
    return (u16)(r >> 16);
}
__device__ inline float bf2f(u16 h) {
    union { unsigned u; float f; } x; x.u = ((unsigned)h) << 16;
    return x.f;
}
// clamp raw bf16 to >= bf16(1e-6)=0x3586; signed compare handles negatives.
__device__ inline bf16x8 clampbf8(bf16x8 v) {
#pragma unroll
    for (int i = 0; i < 8; ++i) {
        short t = v[i];
        v[i] = (t < (short)0x3586) ? (short)0x3586 : t;
    }
    return v;
}

#define MFMA16(a, b, c) __builtin_amdgcn_mfma_f32_16x16x32_bf16((a), (b), (c), 0, 0, 0)

// ---------------------------------------------------------------------------
// convert_x: x fp32 [s][d][n] -> xd bf16 CLAMPED [s][d][n] + xT bf16 RAW
// [s][n][d]. Both live in d_out. grid (NTOT/64, DD/64, NB).
// ---------------------------------------------------------------------------
__global__ __launch_bounds__(256) void convert_x_kernel(const float* __restrict__ x,
                                                        u16* __restrict__ xd,
                                                        u16* __restrict__ xT) {
    int s = blockIdx.z, d0 = blockIdx.y * 64, n0 = blockIdx.x * 64;
    const float* xp = x + ((size_t)s * DD + d0) * NTOT + n0;
    u16* xdp = xd + ((size_t)s * DD + d0) * NTOT + n0;
    u16* xtp = xT + ((size_t)s * NTOT + n0) * DD + d0;
    __shared__ u16 L[64][66];
    int tid = threadIdx.x;
#pragma unroll
    for (int k = 0; k < 4; ++k) {
        int f4 = tid + k * 256;
        int dr = f4 >> 4, c4 = (f4 & 15) * 4;
        float4 v = *(const float4*)&xp[(size_t)dr * NTOT + c4];
        u16 h0 = f2bf(v.x), h1 = f2bf(v.y), h2 = f2bf(v.z), h3 = f2bf(v.w);
        xdp[(size_t)dr * NTOT + c4 + 0] = f2bf(fmaxf(v.x, EPSV));
        xdp[(size_t)dr * NTOT + c4 + 1] = f2bf(fmaxf(v.y, EPSV));
        xdp[(size_t)dr * NTOT + c4 + 2] = f2bf(fmaxf(v.z, EPSV));
        xdp[(size_t)dr * NTOT + c4 + 3] = f2bf(fmaxf(v.w, EPSV));
        L[dr][c4 + 0] = h0; L[dr][c4 + 1] = h1;
        L[dr][c4 + 2] = h2; L[dr][c4 + 3] = h3;
    }
    __syncthreads();
#pragma unroll
    for (int k = 0; k < 2; ++k) {
        int f8 = tid + k * 256;
        int nr = f8 >> 3, d8 = (f8 & 7) * 8;
        us8 w;
#pragma unroll
        for (int i = 0; i < 8; ++i) w[i] = L[d8 + i][nr];
        *(us8*)&xtp[(size_t)nr * DD + d8] = w;
    }
}

// ---------------------------------------------------------------------------
// colnorm: dst[:,r] = src[:,r] / max(||src[:,r]||, 1e-12) per (batch, r).
// ---------------------------------------------------------------------------
__global__ __launch_bounds__(64) void colnorm_kernel(const float* __restrict__ src,
                                                     float* __restrict__ dst) {
    int col = blockIdx.x;
    int s = col >> 6, r = col & 63;
    const float* p = src + (size_t)s * DD * RR + r;
    float* q = dst + (size_t)s * DD * RR + r;
    int lane = threadIdx.x;
    float v[8];
    float ss = 0.f;
#pragma unroll
    for (int k = 0; k < 8; ++k) {
        v[k] = p[(size_t)(lane + 64 * k) * RR];
        ss += v[k] * v[k];
    }
#pragma unroll
    for (int m = 1; m < 64; m <<= 1) ss += __shfl_xor(ss, m);
    float inv = 1.f / fmaxf(sqrtf(ss), 1e-12f);
#pragma unroll
    for (int k = 0; k < 8; ++k)
        q[(size_t)(lane + 64 * k) * RR] = v[k] * inv;
}

// ---------------------------------------------------------------------------
// bcast0: b fp32 [d][r] -> b_bf [d][r], bT_bf [r][d]. grid (NB), 256 thr.
// ---------------------------------------------------------------------------
__global__ __launch_bounds__(256) void bcast0_kernel(const float* __restrict__ b,
                                                     u16* __restrict__ b_bf,
                                                     u16* __restrict__ bT_bf) {
    int s = blockIdx.x, tid = threadIdx.x;
    const float* bp = b + (size_t)s * DD * RR;
    u16* bb = b_bf + (size_t)s * DD * RR;
    u16* bt = bT_bf + (size_t)s * RR * DD;
    for (int i = tid; i < DD * RR; i += 256) {
        int d = i >> 6, r = i & 63;
        u16 h = f2bf(bp[i]);
        bb[i] = h;
        bt[r * DD + d] = h;
    }
}

// ---------------------------------------------------------------------------
// gram: btb_bf[k][j] = bf16( sum_d bT[k][d]*bT[j][d] )  via MFMA, K=512.
// grid (NB), 256 thr.
// ---------------------------------------------------------------------------
__global__ __launch_bounds__(256) void gram_kernel(const u16* __restrict__ bT_bf,
                                                   u16* __restrict__ btb_bf) {
    int s = blockIdx.x;
    int tid = threadIdx.x;
    int w = tid >> 6, lane = tid & 63, g = lane >> 4, l15 = lane & 15;
    const u16* bt = bT_bf + (size_t)s * RR * DD;
    f32x4 zero = {0.f, 0.f, 0.f, 0.f};
    f32x4 acc[4];
#pragma unroll
    for (int cs = 0; cs < 4; ++cs) acc[cs] = zero;
    for (int k0 = 0; k0 < DD; k0 += 32) {
        bf16x8 a = *(const bf16x8*)&bt[(w * 16 + l15) * DD + k0 + g * 8];
        bf16x8 b[4];
#pragma unroll
        for (int cs = 0; cs < 4; ++cs)
            b[cs] = *(const bf16x8*)&bt[(cs * 16 + l15) * DD + k0 + g * 8];
#pragma unroll
        for (int cs = 0; cs < 4; ++cs) acc[cs] = MFMA16(a, b[cs], acc[cs]);
    }
    u16* op = btb_bf + (size_t)s * RR * RR;
#pragma unroll
    for (int cs = 0; cs < 4; ++cs)
#pragma unroll
        for (int e = 0; e < 4; ++e)
            op[(w * 16 + g * 4 + e) * RR + cs * 16 + l15] = f2bf(acc[cs][e]);
}

// ---------------------------------------------------------------------------
// init_mfma: coef = softmax_r(x^T b) via MFMA on raw xT; pipelined K-loop.
// Writes cTf [r][n] and cnb [n][r]. grid (NTOT/128, NB), 256 thr.
// ---------------------------------------------------------------------------
__global__ __launch_bounds__(256) void init_mfma_kernel(const u16* __restrict__ xT,
                                                        const u16* __restrict__ bT,
                                                        u16* __restrict__ cT,
                                                        u16* __restrict__ cnb) {
    int s = blockIdx.y;
    int n0 = blockIdx.x * 128;
    int tid = threadIdx.x;
    int w = tid >> 6, lane = tid & 63, g = lane >> 4, l15 = lane & 15;
    int nw = n0 + w * 32;
    const u16* xTp = xT + (size_t)s * NTOT * DD;
    const u16* bTp = bT + (size_t)s * RR * DD;
    u16* cTp = cT + (size_t)s * RR * NTOT;
    u16* cnp = cnb + (size_t)s * NTOT * RR;

    f32x4 zero = {0.f, 0.f, 0.f, 0.f};
    f32x4 acc[4][2];
#pragma unroll
    for (int rs = 0; rs < 4; ++rs)
#pragma unroll
        for (int ns = 0; ns < 2; ++ns) acc[rs][ns] = zero;

    // pipelined: 16 k-steps of 32 -> 8 pairs, two named buffer sets
    bf16x8 aA[4], bA[2], aB[4], bB[2];
#pragma unroll
    for (int rs = 0; rs < 4; ++rs)
        aA[rs] = *(const bf16x8*)&bTp[(rs * 16 + l15) * DD + g * 8];
#pragma unroll
    for (int ns = 0; ns < 2; ++ns)
        bA[ns] = *(const bf16x8*)&xTp[(size_t)(nw + ns * 16 + l15) * DD + g * 8];
#pragma unroll
    for (int i = 0; i < 8; ++i) {
        int kB = i * 64 + 32;
#pragma unroll
        for (int rs = 0; rs < 4; ++rs)
            aB[rs] = *(const bf16x8*)&bTp[(rs * 16 + l15) * DD + kB + g * 8];
#pragma unroll
        for (int ns = 0; ns < 2; ++ns)
            bB[ns] = *(const bf16x8*)&xTp[(size_t)(nw + ns * 16 + l15) * DD + kB + g * 8];
#pragma unroll
        for (int rs = 0; rs < 4; ++rs)
#pragma unroll
            for (int ns = 0; ns < 2; ++ns)
                acc[rs][ns] = MFMA16(aA[rs], bA[ns], acc[rs][ns]);
        int kA = (i < 7) ? i * 64 + 64 : i * 64;   // clamped (redundant tail)
#pragma unroll
        for (int rs = 0; rs < 4; ++rs)
            aA[rs] = *(const bf16x8*)&bTp[(rs * 16 + l15) * DD + kA + g * 8];
#pragma unroll
        for (int ns = 0; ns < 2; ++ns)
            bA[ns] = *(const bf16x8*)&xTp[(size_t)(nw + ns * 16 + l15) * DD + kA + g * 8];
#pragma unroll
        for (int rs = 0; rs < 4; ++rs)
#pragma unroll
            for (int ns = 0; ns < 2; ++ns)
                acc[rs][ns] = MFMA16(aB[rs], bB[ns], acc[rs][ns]);
    }

#pragma unroll
    for (int ns = 0; ns < 2; ++ns) {
        int n = nw + ns * 16 + l15;
        float m = acc[0][ns][0];
#pragma unroll
        for (int rs = 0; rs < 4; ++rs)
#pragma unroll
            for (int e = 0; e < 4; ++e) m = fmaxf(m, acc[rs][ns][e]);
        m = fmaxf(m, __shfl_xor(m, 16));
        m = fmaxf(m, __shfl_xor(m, 32));
        float ev[4][4];
        float ssum = 0.f;
#pragma unroll
        for (int rs = 0; rs < 4; ++rs)
#pragma unroll
            for (int e = 0; e < 4; ++e) {
                ev[rs][e] = __expf(acc[rs][ns][e] - m);
                ssum += ev[rs][e];
            }
        ssum += __shfl_xor(ssum, 16);
        ssum += __shfl_xor(ssum, 32);
        float inv = 1.f / ssum;
#pragma unroll
        for (int rs = 0; rs < 4; ++rs) {
            us4 pack;
#pragma unroll
            for (int e = 0; e < 4; ++e) {
                u16 h = f2bf(ev[rs][e] * inv);
                cTp[(size_t)(rs * 16 + g * 4 + e) * NTOT + n] = h;
                pack[e] = h;
            }
            *(us4*)&cnp[(size_t)n * RR + rs * 16 + g * 4] = pack;
        }
    }
}

// ---------------------------------------------------------------------------
// xtb_mfma: fused denC + numC + c-update; pipelined phase-2 K-loop.
// grid (NTOT/128, NB), 256 thr.
// ---------------------------------------------------------------------------
template <int CLAMPC, int CLAMP_OUT, int WRITE_CT>
__global__ __launch_bounds__(256) void xtb_mfma_kernel(const u16* __restrict__ xT,
                                                       const u16* __restrict__ bT,
                                                       const u16* __restrict__ btbbf,
                                                       u16* __restrict__ cnb,
                                                       u16* __restrict__ cT) {
    int s = blockIdx.y;
    int n0 = blockIdx.x * 128;
    int tid = threadIdx.x;
    int w = tid >> 6, lane = tid & 63, g = lane >> 4, l15 = lane & 15;
    int nw = n0 + w * 32;
    const u16* xTp = xT + (size_t)s * NTOT * DD;
    const u16* bTp = bT + (size_t)s * RR * DD;
    const u16* bb = btbbf + (size_t)s * RR * RR;
    u16* cnp = cnb + (size_t)s * NTOT * RR;
    u16* cTp = cT + (size_t)s * RR * NTOT;

    f32x4 zero = {0.f, 0.f, 0.f, 0.f};
    f32x4 accD[4][2], accT[4][2];
#pragma unroll
    for (int rs = 0; rs < 4; ++rs)
#pragma unroll
        for (int ns = 0; ns < 2; ++ns) { accD[rs][ns] = zero; accT[rs][ns] = zero; }

    // phase 1: den (K=64 over r'; cnb holds prev c, clamp-staged)
#pragma unroll
    for (int k0 = 0; k0 < 64; k0 += 32) {
        bf16x8 a[4], b[2];
#pragma unroll
        for (int rs = 0; rs < 4; ++rs)
            a[rs] = *(const bf16x8*)&bb[(rs * 16 + l15) * RR + k0 + g * 8];
#pragma unroll
        for (int ns = 0; ns < 2; ++ns)
            b[ns] = *(const bf16x8*)&cnp[(size_t)(nw + ns * 16 + l15) * RR + k0 + g * 8];
#pragma unroll
        for (int rs = 0; rs < 4; ++rs)
#pragma unroll
            for (int ns = 0; ns < 2; ++ns)
                accD[rs][ns] = MFMA16(a[rs], b[ns], accD[rs][ns]);
    }

    // phase 2: T = b^T clamp(x), pipelined 16 k-steps of 32 as 8 pairs
    {
        bf16x8 aA[4], bA[2], aB[4], bB[2];
#pragma unroll
        for (int rs = 0; rs < 4; ++rs)
            aA[rs] = *(const bf16x8*)&bTp[(rs * 16 + l15) * DD + g * 8];
#pragma unroll
        for (int ns = 0; ns < 2; ++ns)
            bA[ns] = clampbf8(*(const bf16x8*)&xTp[(size_t)(nw + ns * 16 + l15) * DD + g * 8]);
#pragma unroll
        for (int i = 0; i < 8; ++i) {
            int kB = i * 64 + 32;
#pragma unroll
            for (int rs = 0; rs < 4; ++rs)
                aB[rs] = *(const bf16x8*)&bTp[(rs * 16 + l15) * DD + kB + g * 8];
#pragma unroll
            for (int ns = 0; ns < 2; ++ns)
                bB[ns] = clampbf8(*(const bf16x8*)&xTp[(size_t)(nw + ns * 16 + l15) * DD + kB + g * 8]);
#pragma unroll
            for (int rs = 0; rs < 4; ++rs)
#pragma unroll
                for (int ns = 0; ns < 2; ++ns)
                    accT[rs][ns] = MFMA16(aA[rs], bA[ns], accT[rs][ns]);
            int kA = (i < 7) ? i * 64 + 64 : i * 64;
#pragma unroll
            for (int rs = 0; rs < 4; ++rs)
                aA[rs] = *(const bf16x8*)&bTp[(rs * 16 + l15) * DD + kA + g * 8];
#pragma unroll
            for (int ns = 0; ns < 2; ++ns)
                bA[ns] = clampbf8(*(const bf16x8*)&xTp[(size_t)(nw + ns * 16 + l15) * DD + kA + g * 8]);
#pragma unroll
            for (int rs = 0; rs < 4; ++rs)
#pragma unroll
                for (int ns = 0; ns < 2; ++ns)
                    accT[rs][ns] = MFMA16(aB[rs], bB[ns], accT[rs][ns]);
        }
    }

    // epilogue
#pragma unroll
    for (int ns = 0; ns < 2; ++ns) {
        int n = nw + ns * 16 + l15;
#pragma unroll
        for (int rs = 0; rs < 4; ++rs) {
            us4 pack;
#pragma unroll
            for (int e = 0; e < 4; ++e) {
                int r = rs * 16 + g * 4 + e;
                size_t off = (size_t)r * NTOT + n;
                float cin = bf2f(cTp[off]);
                if (CLAMPC) cin = fmaxf(cin, EPSV);
                float v = cin * accT[rs][ns][e] / (accD[rs][ns][e] + EPSV);
                u16 h = f2bf(v);
                if (WRITE_CT) cTp[off] = h;
                if (CLAMP_OUT) h = (h < (u16)0x3586u) ? (u16)0x3586u : h;  // v>0
                pack[e] = h;
            }
            *(us4*)&cnp[(size_t)n * RR + rs * 16 + g * 4] = pack;
        }
    }
}

// ---------------------------------------------------------------------------
// ctc_mfma: CtC[i][j] += sum_n c[n][i]*c[n][j]. Pipelined; K-split atomics.
// grid (128, NB), chunk 512, 256 thr.
// ---------------------------------------------------------------------------
__global__ __launch_bounds__(256) void ctc_mfma_kernel(const u16* __restrict__ cT,
                                                       float* __restrict__ ctc) {
    int s = blockIdx.y;
    int kbase = blockIdx.x * 512;
    int tid = threadIdx.x;
    int w = tid >> 6, lane = tid & 63, g = lane >> 4, l15 = lane & 15;
    const u16* cTp = cT + (size_t)s * RR * NTOT;
    const u16* arow = cTp + (size_t)(w * 16 + l15) * NTOT;
    f32x4 zero = {0.f, 0.f, 0.f, 0.f};
    f32x4 acc[4];
#pragma unroll
    for (int cs = 0; cs < 4; ++cs) acc[cs] = zero;

    bf16x8 aA, bA[4], aB, bB[4];
    aA = *(const bf16x8*)&arow[kbase + g * 8];
#pragma unroll
    for (int cs = 0; cs < 4; ++cs)
        bA[cs] = *(const bf16x8*)&cTp[(size_t)(cs * 16 + l15) * NTOT + kbase + g * 8];
#pragma unroll
    for (int i = 0; i < 8; ++i) {
        int kB = kbase + i * 64 + 32;
        aB = *(const bf16x8*)&arow[kB + g * 8];
#pragma unroll
        for (int cs = 0; cs < 4; ++cs)
            bB[cs] = *(const bf16x8*)&cTp[(size_t)(cs * 16 + l15) * NTOT + kB + g * 8];
#pragma unroll
        for (int cs = 0; cs < 4; ++cs) acc[cs] = MFMA16(aA, bA[cs], acc[cs]);
        int kA = (i < 7) ? kbase + i * 64 + 64 : kbase;
        aA = *(const bf16x8*)&arow[kA + g * 8];
#pragma unroll
        for (int cs = 0; cs < 4; ++cs)
            bA[cs] = *(const bf16x8*)&cTp[(size_t)(cs * 16 + l15) * NTOT + kA + g * 8];
#pragma unroll
        for (int cs = 0; cs < 4; ++cs) acc[cs] = MFMA16(aB, bB[cs], acc[cs]);
    }
    float* op = ctc + (size_t)s * RR * RR;
#pragma unroll
    for (int cs = 0; cs < 4; ++cs)
#pragma unroll
        for (int e = 0; e < 4; ++e)
            atomicAdd(&op[(w * 16 + g * 4 + e) * RR + cs * 16 + l15], acc[cs][e]);
}

// ---------------------------------------------------------------------------
// xtc_mfma: numB[d][r] += sum_n xd[d][n]*c[n][r]. Pipelined, 256 thr,
// grid (32 ksplit, 8 dtile, NB) = 512 blocks, chunk 2048.
// ---------------------------------------------------------------------------
__global__ __launch_bounds__(256) void xtc_mfma_kernel(const u16* __restrict__ xd,
                                                       const u16* __restrict__ cT,
                                                       float* __restrict__ numB) {
    int s = blockIdx.z;
    int dtile = blockIdx.y * 64;
    int kbase = blockIdx.x * 2048;
    int tid = threadIdx.x;
    int w = tid >> 6, lane = tid & 63, g = lane >> 4, l15 = lane & 15;
    const u16* arow = xd + (size_t)s * DD * NTOT + (size_t)(dtile + w * 16 + l15) * NTOT;
    const u16* cTp = cT + (size_t)s * RR * NTOT;
    f32x4 zero = {0.f, 0.f, 0.f, 0.f};
    f32x4 acc[4];
#pragma unroll
    for (int rs = 0; rs < 4; ++rs) acc[rs] = zero;

    bf16x8 aA, bA[4], aB, bB[4];
    aA = *(const bf16x8*)&arow[kbase + g * 8];
#pragma unroll
    for (int rs = 0; rs < 4; ++rs)
        bA[rs] = *(const bf16x8*)&cTp[(size_t)(rs * 16 + l15) * NTOT + kbase + g * 8];
#pragma unroll
    for (int i = 0; i < 32; ++i) {
        int kB = kbase + i * 64 + 32;
        aB = *(const bf16x8*)&arow[kB + g * 8];
#pragma unroll
        for (int rs = 0; rs < 4; ++rs)
            bB[rs] = *(const bf16x8*)&cTp[(size_t)(rs * 16 + l15) * NTOT + kB + g * 8];
#pragma unroll
        for (int rs = 0; rs < 4; ++rs) acc[rs] = MFMA16(aA, bA[rs], acc[rs]);
        int kA = (i < 31) ? kbase + i * 64 + 64 : kbase;
        aA = *(const bf16x8*)&arow[kA + g * 8];
#pragma unroll
        for (int rs = 0; rs < 4; ++rs)
            bA[rs] = *(const bf16x8*)&cTp[(size_t)(rs * 16 + l15) * NTOT + kA + g * 8];
#pragma unroll
        for (int rs = 0; rs < 4; ++rs) acc[rs] = MFMA16(aB, bB[rs], acc[rs]);
    }
    float* op = numB + (size_t)s * DD * RR;
#pragma unroll
    for (int rs = 0; rs < 4; ++rs)
#pragma unroll
        for (int e = 0; e < 4; ++e)
            atomicAdd(&op[(dtile + w * 16 + g * 4 + e) * RR + rs * 16 + l15], acc[rs][e]);
}

// ---------------------------------------------------------------------------
// bupd_a: bnew = max(b*numB/(b@CtC+EPS), EPS) in-place + column-norm^2
// partials. grid (8, NB), 256 thr.
// ---------------------------------------------------------------------------
__global__ __launch_bounds__(256) void bupd_a_kernel(float* __restrict__ b0,
                                                     const float* __restrict__ numB,
                                                     const float* __restrict__ ctcG,
                                                     float* __restrict__ norm2p) {
    int s = blockIdx.y;
    int d0 = blockIdx.x * 64;
    float* bp = b0 + ((size_t)s * DD + d0) * RR;
    const float* np_ = numB + ((size_t)s * DD + d0) * RR;
    const float* cc = ctcG + (size_t)s * RR * RR;
    __shared__ __align__(16) float Bsh[64][68];
    __shared__ __align__(16) float Ct[64][68];
    __shared__ float red[16][64];
    int tid = threadIdx.x, tx = tid & 15, ty = tid >> 4;
#pragma unroll
    for (int k = 0; k < 16; ++k) {
        int idx = tid + k * 256;
        int r_ = idx >> 6, col = idx & 63;
        Bsh[r_][col] = bp[idx];
        Ct[r_][col] = cc[idx];
    }
    __syncthreads();
    float part[4] = {};
#pragma unroll
    for (int i = 0; i < 4; ++i) {
        int d = 4 * ty + i;
        float den[4] = {};
#pragma unroll
        for (int k = 0; k < 64; ++k) {
            float bv = Bsh[d][k];
            float4 ct = *(const float4*)&Ct[k][4 * tx];
            den[0] += bv * ct.x;
            den[1] += bv * ct.y;
            den[2] += bv * ct.z;
            den[3] += bv * ct.w;
        }
        float4 b4 = *(const float4*)&Bsh[d][4 * tx];
        float4 n4 = *(const float4*)&np_[(size_t)d * RR + 4 * tx];
        float4 o;
        o.x = fmaxf(b4.x * n4.x / (den[0] + EPSV), EPSV);
        o.y = fmaxf(b4.y * n4.y / (den[1] + EPSV), EPSV);
        o.z = fmaxf(b4.z * n4.z / (den[2] + EPSV), EPSV);
        o.w = fmaxf(b4.w * n4.w / (den[3] + EPSV), EPSV);
        *(float4*)&bp[(size_t)d * RR + 4 * tx] = o;
        part[0] += o.x * o.x; part[1] += o.y * o.y;
        part[2] += o.z * o.z; part[3] += o.w * o.w;
    }
#pragma unroll
    for (int j = 0; j < 4; ++j) red[ty][4 * tx + j] = part[j];
    __syncthreads();
    if (tid < 64) {
        float ssum = 0.f;
#pragma unroll
        for (int k = 0; k < 16; ++k) ssum += red[k][tid];
        norm2p[((size_t)s * 8 + blockIdx.x) * 64 + tid] = ssum;
    }
}

// ---------------------------------------------------------------------------
// bupd_c: inv = 1/max(sqrt(sum norm2p),1e-12); b0 *= inv; write b_bf, bT_bf.
// grid (8, NB), 256 thr.
// ---------------------------------------------------------------------------
__global__ __launch_bounds__(256) void bupd_c_kernel(float* __restrict__ b0,
                                                     const float* __restrict__ norm2p,
                                                     u16* __restrict__ b_bf,
                                                     u16* __restrict__ bT_bf) {
    int s = blockIdx.y;
    int d0 = blockIdx.x * 64;
    float* bp = b0 + ((size_t)s * DD + d0) * RR;
    u16* bb = b_bf + ((size_t)s * DD + d0) * RR;
    u16* bt = bT_bf + (size_t)s * RR * DD;
    __shared__ float invl[64];
    int tid = threadIdx.x, tx = tid & 15, ty = tid >> 4;
    if (tid < 64) {
        float t = 0.f;
#pragma unroll
        for (int k = 0; k < 8; ++k) t += norm2p[((size_t)s * 8 + k) * 64 + tid];
        invl[tid] = 1.f / fmaxf(sqrtf(t), 1e-12f);
    }
    __syncthreads();
#pragma unroll
    for (int i = 0; i < 4; ++i) {
        int d = 4 * ty + i;
        float4 v = *(const float4*)&bp[(size_t)d * RR + 4 * tx];
        v.x *= invl[4 * tx + 0];
        v.y *= invl[4 * tx + 1];
        v.z *= invl[4 * tx + 2];
        v.w *= invl[4 * tx + 3];
        *(float4*)&bp[(size_t)d * RR + 4 * tx] = v;
        us4 pack;
        pack[0] = f2bf(v.x); pack[1] = f2bf(v.y);
        pack[2] = f2bf(v.z); pack[3] = f2bf(v.w);
        *(us4*)&bb[(size_t)d * RR + 4 * tx] = pack;
        bt[(4 * tx + 0) * DD + d0 + d] = pack[0];
        bt[(4 * tx + 1) * DD + d0 + d] = pack[1];
        bt[(4 * tx + 2) * DD + d0 + d] = pack[2];
        bt[(4 * tx + 3) * DD + d0 + d] = pack[3];
    }
}

// ---------------------------------------------------------------------------
// xhat_mfma: out[d][n] = sum_r b[d][r]*c_new[n][r]. K=64.
// grid (NTOT/64, DD/64, NB).
// ---------------------------------------------------------------------------
__global__ __launch_bounds__(256) void xhat_mfma_kernel(const u16* __restrict__ b_bf,
                                                        const u16* __restrict__ cnb,
                                                        float* __restrict__ outp) {
    int s = blockIdx.z;
    int d0 = blockIdx.y * 64;
    int n0 = blockIdx.x * 64;
    int tid = threadIdx.x;
    int w = tid >> 6, lane = tid & 63, g = lane >> 4, l15 = lane & 15;
    const u16* bp = b_bf + (size_t)s * DD * RR;
    const u16* cp = cnb + (size_t)s * NTOT * RR;
    f32x4 zero = {0.f, 0.f, 0.f, 0.f};
    f32x4 acc[4];
#pragma unroll
    for (int ns = 0; ns < 4; ++ns) acc[ns] = zero;
#pragma unroll
    for (int k0 = 0; k0 < 64; k0 += 32) {
        bf16x8 a = *(const bf16x8*)&bp[(d0 + w * 16 + l15) * RR + k0 + g * 8];
        bf16x8 b[4];
#pragma unroll
        for (int ns = 0; ns < 4; ++ns)
            b[ns] = *(const bf16x8*)&cp[(size_t)(n0 + ns * 16 + l15) * RR + k0 + g * 8];
#pragma unroll
        for (int ns = 0; ns < 4; ++ns) acc[ns] = MFMA16(a, b[ns], acc[ns]);
    }
    float* op = outp + (size_t)s * DD * NTOT;
#pragma unroll
    for (int ns = 0; ns < 4; ++ns)
#pragma unroll
        for (int e = 0; e < 4; ++e)
            op[(size_t)(d0 + w * 16 + g * 4 + e) * NTOT + n0 + ns * 16 + l15] = acc[ns][e];
}

// ---------------------------------------------------------------------------
extern "C" void kernel_launch(void* const* d_in, const int* in_sizes, int n_in,
                              void* d_out, int out_size, void* d_ws, size_t ws_size,
                              hipStream_t stream) {
    const float* x = (const float*)d_in[0];      // (2,512,65536) fp32
    const float* bases = (const float*)d_in[1];  // (2,512,64)
    float* out = (float*)d_out;
    char* ws = (char*)d_ws;

    // out doubles as bf16 x storage until xhat overwrites it
    u16* xT = (u16*)d_out;                             // [NB][NTOT][DD] RAW
    u16* xd = (u16*)d_out + (size_t)NB * NTOT * DD;    // [NB][DD][NTOT] clamped

    // ws layout (<= 34,406,400 B proven-safe footprint)
    u16* cTf = (u16*)ws;                          // 16,777,216
    u16* cnb = (u16*)(ws + 16777216);             // 16,777,216
    float* b0 = (float*)(ws + 33554432);          //    262,144
    float* ctc = (float*)(ws + 33816576);         //     32,768
    float* nB = (float*)(ws + 33849344);          //    262,144 (contig w/ ctc)
    u16* bT_bf = (u16*)(ws + 34111488);           //    131,072
    u16* b_bf = (u16*)(ws + 34242560);            //    131,072
    u16* btb_bf = (u16*)(ws + 34373632);          //     16,384
    float* norm2p = (float*)(ws + 34390016);      //      4,096  -> 34,394,112

    // 1) bf16 copies of x into out (xT raw, xd clamped)
    convert_x_kernel<<<dim3(NTOT / 64, DD / 64, NB), 256, 0, stream>>>(x, xd, xT);

    // 2) b = l2norm(bases); casts; BtB via MFMA gram
    colnorm_kernel<<<NB * RR, 64, 0, stream>>>(bases, b0);
    bcast0_kernel<<<NB, 256, 0, stream>>>(b0, b_bf, bT_bf);
    gram_kernel<<<NB, 256, 0, stream>>>(bT_bf, btb_bf);

    // 3) coef = softmax(x^T b) via MFMA on raw xT
    init_mfma_kernel<<<dim3(NTOT / 128, NB), 256, 0, stream>>>(xT, bT_bf, cTf, cnb);

    // 4) 6 MU steps
    for (int step = 0; step < 6; ++step) {
        if (step > 0)
            xtb_mfma_kernel<1, 1, 1><<<dim3(NTOT / 128, NB), 256, 0, stream>>>(
                xT, bT_bf, btb_bf, cnb, cTf);
        else
            xtb_mfma_kernel<0, 1, 1><<<dim3(NTOT / 128, NB), 256, 0, stream>>>(
                xT, bT_bf, btb_bf, cnb, cTf);
        hipMemsetAsync(ctc, 0, 32768 + 262144, stream);   // ctc + numB contiguous
        ctc_mfma_kernel<<<dim3(128, NB), 256, 0, stream>>>(cTf, ctc);
        xtc_mfma_kernel<<<dim3(32, 8, NB), 256, 0, stream>>>(xd, cTf, nB);
        bupd_a_kernel<<<dim3(8, NB), 256, 0, stream>>>(b0, nB, ctc, norm2p);
        bupd_c_kernel<<<dim3(8, NB), 256, 0, stream>>>(b0, norm2p, b_bf, bT_bf);
        gram_kernel<<<NB, 256, 0, stream>>>(bT_bf, btb_bf);
    }

    // 5) compute_coef: cnb <- c_new (unclamped) for xhat
    xtb_mfma_kernel<1, 0, 0><<<dim3(NTOT / 128, NB), 256, 0, stream>>>(
        xT, bT_bf, btb_bf, cnb, cTf);

    // 6) x_hat = b @ c_new^T
    xhat_mfma_kernel<<<dim3(NTOT / 64, DD / 64, NB), 256, 0, stream>>>(b_bf, cnb, out);
}